// Round 17
// baseline (163.320 us; speedup 1.0000x reference)
//
#include <hip/hip_runtime.h>
#include <hip/hip_bf16.h>

#define B_ 4
#define T_ 2048
#define C_ 1024
#define H_ 16
#define D_ 64
#define M_ (B_*T_)   // 8192

typedef __bf16 bf16x8 __attribute__((ext_vector_type(8)));
typedef float  f32x4  __attribute__((ext_vector_type(4)));
typedef float  f32x16 __attribute__((ext_vector_type(16)));

__device__ __forceinline__ unsigned short f2bf(float f) {
  unsigned u = __builtin_bit_cast(unsigned, f);
  u += 0x7FFF + ((u >> 16) & 1);   // round-to-nearest-even
  return (unsigned short)(u >> 16);
}

__device__ __forceinline__ float exp2fast(float x) {
#if __has_builtin(__builtin_amdgcn_exp2f)
  return __builtin_amdgcn_exp2f(x);
#else
  float r; asm("v_exp_f32 %0, %1" : "=v"(r) : "v"(x)); return r;
#endif
}

__device__ __forceinline__ float max3f(float a, float b, float c) {
  return fmaxf(fmaxf(a, b), c);   // fuses to v_max3_f32
}

__device__ __forceinline__ void gload_lds16(const void* g, void* l) {
  __builtin_amdgcn_global_load_lds(
      (const __attribute__((address_space(1))) void*)g,
      (__attribute__((address_space(3))) void*)l, 16, 0, 0);
}

// ------------- fused prep: weight transpose+convert (z=0..3) + x f32->bf16 (z=4..11) -----
__global__ void prep(const float* __restrict__ x,
                     const float* __restrict__ w0, const float* __restrict__ w1,
                     const float* __restrict__ w2, const float* __restrict__ w3,
                     unsigned short* __restrict__ xb,
                     unsigned short* __restrict__ tqkv,
                     unsigned short* __restrict__ tp) {
  __shared__ float tile[32][33];
  const int z = blockIdx.z;
  if (z >= 4) {
    int tid = threadIdx.y * 32 + threadIdx.x;
    int i = (((z - 4) * 1024) + (blockIdx.y * 32 + blockIdx.x)) * 256 + tid;
    float4 v = ((const float4*)x)[i];
    ushort4 o;
    o.x = f2bf(v.x); o.y = f2bf(v.y); o.z = f2bf(v.z); o.w = f2bf(v.w);
    ((ushort4*)xb)[i] = o;
    return;
  }
  const float* src; unsigned short* dst;
  switch (z) {
    case 0: src = w0; dst = tqkv; break;
    case 1: src = w1; dst = tqkv + (size_t)C_ * C_; break;
    case 2: src = w2; dst = tqkv + (size_t)2 * C_ * C_; break;
    default: src = w3; dst = tp; break;
  }
  int bx = blockIdx.x * 32;  // n base
  int by = blockIdx.y * 32;  // k base
  int tx = threadIdx.x, ty = threadIdx.y;
  #pragma unroll
  for (int j = 0; j < 4; ++j)
    tile[ty + 8*j][tx] = src[(size_t)(by + ty + 8*j) * C_ + bx + tx];
  __syncthreads();
  #pragma unroll
  for (int j = 0; j < 4; ++j)
    dst[(size_t)(bx + ty + 8*j) * C_ + by + tx] = f2bf(tile[tx][ty + 8*j]);
}

// ---------------- fused QKV GEMM: xb[M][K] @ wqkvt[3N][K]^T ----------------
__global__ __launch_bounds__(256, 2)
void gemm_qkv(const unsigned short* __restrict__ A,
              const unsigned short* __restrict__ Bt,
              const float* __restrict__ bq, const float* __restrict__ bk,
              const float* __restrict__ bv,
              unsigned short* __restrict__ qout, unsigned short* __restrict__ kout,
              unsigned short* __restrict__ vout, float qscale)
{
  __shared__ unsigned short ls[2 * 128 * 64];   // 32KB
  unsigned short* lsA = ls;
  unsigned short* lsB = ls + 128 * 64;
  const int wave = threadIdx.x >> 6;
  const int lane = threadIdx.x & 63;
  const int rowBase = blockIdx.y * 128;
  const int colBase = blockIdx.x * 128;
  const int rowOff = (wave >> 1) * 64;
  const int colOff = (wave & 1) * 64;
  const int lr = lane & 15;
  const int lg = lane >> 4;

  f32x4 acc[4][4] = {};

  const int chunkRow = lane >> 3;
  const int srcColE  = (((lane & 7) ^ (lane >> 3)) * 8);

  for (int k0 = 0; k0 < C_; k0 += 64) {
    #pragma unroll
    for (int c = 0; c < 4; ++c) {
      int chunk = c * 4 + wave;
      int r = chunk * 8 + chunkRow;
      gload_lds16(A  + (size_t)(rowBase + r) * C_ + k0 + srcColE, &lsA[chunk * 512]);
      gload_lds16(Bt + (size_t)(colBase + r) * C_ + k0 + srcColE, &lsB[chunk * 512]);
    }
    __syncthreads();
    #pragma unroll
    for (int kk = 0; kk < 2; ++kk) {
      bf16x8 af[4], bfr[4];
      const int kbyte = (kk * 32 + lg * 8) * 2;
      #pragma unroll
      for (int m = 0; m < 4; ++m) {
        int row = rowOff + m * 16 + lr;
        af[m] = *(const bf16x8*)((const char*)lsA + row * 128 + (kbyte ^ ((row & 7) << 4)));
      }
      #pragma unroll
      for (int n = 0; n < 4; ++n) {
        int row = colOff + n * 16 + lr;
        bfr[n] = *(const bf16x8*)((const char*)lsB + row * 128 + (kbyte ^ ((row & 7) << 4)));
      }
      #pragma unroll
      for (int m = 0; m < 4; ++m)
        #pragma unroll
        for (int n = 0; n < 4; ++n)
          acc[m][n] = __builtin_amdgcn_mfma_f32_16x16x32_bf16(af[m], bfr[n], acc[m][n], 0, 0, 0);
    }
    __syncthreads();
  }

  const int mid = colBase >> 10;                 // 0=Q 1=K 2=V (block-uniform)
  const float* bias = (mid == 0) ? bq : (mid == 1) ? bk : bv;
  const float oscale = (mid == 0) ? qscale : 1.f;
  unsigned short* outp = (mid == 0) ? qout : (mid == 1) ? kout : vout;

  char* rpb = (char*)(ls + wave * 4096);         // per-wave 8KB repack region
  const int colW = colBase + colOff;
  const int h  = (colW & 1023) >> 6;
  const int b  = (rowBase + rowOff) >> 11;
  const int tb = (rowBase + rowOff) & 2047;

  #pragma unroll
  for (int m = 0; m < 4; ++m)
    #pragma unroll
    for (int n = 0; n < 4; ++n) {
      int colL = n * 16 + lr;
      float bs = bias[(colW + colL) & 1023];
      #pragma unroll
      for (int j = 0; j < 4; ++j) {
        int rowL = m * 16 + lg * 4 + j;
        unsigned short v = f2bf((acc[m][n][j] + bs) * oscale);
        int wr, wc;
        if (mid == 2) {
          int t2 = (rowL & ~12) | ((rowL & 4) << 1) | ((rowL & 8) >> 1);
          wr = colL; wc = t2;
        } else {
          wr = rowL; wc = colL;
        }
        *(unsigned short*)(rpb + wr * 128 + ((wc * 2) ^ ((wr & 7) << 4))) = v;
      }
    }

  const int rb = lane >> 3;
  const int g  = lane & 7;
  if (mid == 2) {
    unsigned short* ob = outp + (((size_t)b * H_ + h) * D_) * T_ + tb;
    #pragma unroll
    for (int p = 0; p < 8; ++p) {
      int d = rb + p * 8;
      bf16x8 v = *(const bf16x8*)(rpb + d * 128 + ((g * 16) ^ ((d & 7) << 4)));
      *(bf16x8*)(ob + (size_t)d * T_ + g * 8) = v;
    }
  } else {
    unsigned short* ob = outp + (((size_t)b * H_ + h) * T_ + tb) * D_;
    #pragma unroll
    for (int p = 0; p < 8; ++p) {
      int r = rb + p * 8;
      bf16x8 v = *(const bf16x8*)(rpb + r * 128 + ((g * 16) ^ ((r & 7) << 4)));
      *(bf16x8*)(ob + (size_t)r * D_ + g * 8) = v;
    }
  }
}

// ---------------- final projection GEMM: yb[M][K] @ wpt[N][K]^T -> f32 ----------------
__global__ __launch_bounds__(256, 2)
void gemm_proj(const unsigned short* __restrict__ A,
               const unsigned short* __restrict__ Bt,
               const float* __restrict__ bias,
               float* __restrict__ Cout)
{
  __shared__ unsigned short lsA[128 * 64];
  __shared__ unsigned short lsB[128 * 64];
  const int wave = threadIdx.x >> 6;
  const int lane = threadIdx.x & 63;
  const int rowBase = blockIdx.y * 128;
  const int colBase = blockIdx.x * 128;
  const int rowOff = (wave >> 1) * 64;
  const int colOff = (wave & 1) * 64;
  const int lr = lane & 15;
  const int lg = lane >> 4;

  f32x4 acc[4][4] = {};

  const int chunkRow = lane >> 3;
  const int srcColE  = (((lane & 7) ^ (lane >> 3)) * 8);

  for (int k0 = 0; k0 < C_; k0 += 64) {
    #pragma unroll
    for (int c = 0; c < 4; ++c) {
      int chunk = c * 4 + wave;
      int r = chunk * 8 + chunkRow;
      gload_lds16(A  + (size_t)(rowBase + r) * C_ + k0 + srcColE, &lsA[chunk * 512]);
      gload_lds16(Bt + (size_t)(colBase + r) * C_ + k0 + srcColE, &lsB[chunk * 512]);
    }
    __syncthreads();
    #pragma unroll
    for (int kk = 0; kk < 2; ++kk) {
      bf16x8 af[4], bfr[4];
      const int kbyte = (kk * 32 + lg * 8) * 2;
      #pragma unroll
      for (int m = 0; m < 4; ++m) {
        int row = rowOff + m * 16 + lr;
        af[m] = *(const bf16x8*)((const char*)lsA + row * 128 + (kbyte ^ ((row & 7) << 4)));
      }
      #pragma unroll
      for (int n = 0; n < 4; ++n) {
        int row = colOff + n * 16 + lr;
        bfr[n] = *(const bf16x8*)((const char*)lsB + row * 128 + (kbyte ^ ((row & 7) << 4)));
      }
      #pragma unroll
      for (int m = 0; m < 4; ++m)
        #pragma unroll
        for (int n = 0; n < 4; ++n)
          acc[m][n] = __builtin_amdgcn_mfma_f32_16x16x32_bf16(af[m], bfr[n], acc[m][n], 0, 0, 0);
    }
    __syncthreads();
  }

  #pragma unroll
  for (int m = 0; m < 4; ++m) {
    int row0 = rowBase + rowOff + m * 16 + lg * 4;
    #pragma unroll
    for (int n = 0; n < 4; ++n) {
      int col = colBase + colOff + n * 16 + lr;
      float bs = bias[col];
      #pragma unroll
      for (int j = 0; j < 4; ++j)
        Cout[(size_t)(row0 + j) * C_ + col] = acc[m][n][j] + bs;
    }
  }
}

// -------- causal flash attention: 8 waves x 32 q-rows (256-row supertile) ----------------
// K 3-buf / V 2-buf LDS staging shared by 8 waves (one gload_lds16 per thread per tile),
// counted vmcnt(1), one barrier per 64-key step. Softmax lane-local (defer-max THR=8,
// v_exp_f32, max3 trees); l accumulated on the MATRIX pipe via mfma(ones, pf, lacc).
__global__ __launch_bounds__(512, 2)
void attn14(const unsigned short* __restrict__ q,
            const unsigned short* __restrict__ k,
            const unsigned short* __restrict__ vp,
            unsigned short* __restrict__ y)
{
  __shared__ unsigned short lsK[3][64 * 64];   // 24 KB
  __shared__ unsigned short lsV[2][64 * 64];   // 16 KB
  const int tid  = threadIdx.x;
  const int wave = tid >> 6;                   // 0..7
  const int lane = tid & 63;
  const int col  = lane & 31;
  const int hi   = lane >> 5;

  const int bid = blockIdx.x;            // 0..511
  const int xcd = bid & 7;
  const int idx = bid >> 3;              // 0..63
  const int bh  = xcd * 8 + (idx & 7);   // 8 heads per XCD
  const int ss  = 7 - (idx >> 3);        // supertile 7..0 (longest first), 256 rows each
  const int b = bh >> 4, h = bh & 15;

  const unsigned short* qh = q  + (size_t)bh * T_ * D_;
  const unsigned short* kh = k  + (size_t)bh * T_ * D_;
  const unsigned short* vh = vp + (size_t)bh * D_ * T_;

  // staging source (inverse-swizzled): 512 threads cover all 64 rows in one issue
  const int srow = tid >> 3;                             // 0..63
  const int srcE = ((tid & 7) * 8) ^ ((srow & 7) << 3);
  const unsigned short* ksrc = kh + srow * D_ + srcE;
  const unsigned short* vsrc = vh + srow * T_ + srcE;

  const int swz = (col & 7) << 4;
  const f32x16 zc = {};

  bf16x8 ones;
  #pragma unroll
  for (int e = 0; e < 8; ++e) ones[e] = (__bf16)1.0f;

  const int q0 = ss * 256 + wave * 32;
  const int nsteps = 4 * ss + 4;

  bf16x8 bqf[4];
  {
    const unsigned short* qrow = qh + (size_t)(q0 + col) * D_ + hi * 8;
    #pragma unroll
    for (int ks = 0; ks < 4; ++ks) bqf[ks] = *(const bf16x8*)(qrow + ks * 16);
  }

  f32x16 ot0 = {}, ot1 = {}, lacc = {};
  float m = -INFINITY;
  bf16x8 pf0, pf1, pf2, pf3;

  auto STAGEK = [&](int t) {
    unsigned short* bK = &lsK[0][0] + (t % 3) * 4096;
    gload_lds16(ksrc + (size_t)t * 64 * D_, bK + tid * 8);
  };
  auto STAGEV = [&](int t) {
    unsigned short* bV = &lsV[0][0] + (t & 1) * 4096;
    gload_lds16(vsrc + t * 64, bV + tid * 8);
  };

  // prologue queue (oldest->newest): K0, V0, K1
  STAGEK(0);
  STAGEV(0);
  STAGEK(1);

  for (int s = 0; s < nsteps; ++s) {
    if (s + 1 < nsteps) {
      asm volatile("s_waitcnt vmcnt(1)" ::: "memory");   // K(s),V(s) landed; K(s+1) in flight
    } else {
      asm volatile("s_waitcnt vmcnt(0)" ::: "memory");   // last step: drain
    }
    __builtin_amdgcn_s_barrier();                         // everyone's tile s landed
    __builtin_amdgcn_sched_barrier(0);
    if (s + 1 < nsteps) STAGEV(s + 1);                    // V 1 ahead
    if (s + 2 < nsteps) STAGEK(s + 2);                    // K 2 ahead

    const int n0 = s * 64;
    if (n0 <= q0 + 31) {
      const bool two = (n0 < q0);
      const unsigned short* baseK = &lsK[0][0] + (s % 3) * 4096;
      const unsigned short* baseV = &lsV[0][0] + (s & 1) * 4096;
      // ---- QK^T ----
      f32x16 st0, st1;
      {
        const char* kb0 = (const char*)baseK + col * 128;
        __builtin_amdgcn_s_setprio(1);
        st0 = __builtin_amdgcn_mfma_f32_32x32x16_bf16(
                *(const bf16x8*)(kb0 + ((0 * 32 + hi * 16) ^ swz)), bqf[0], zc, 0, 0, 0);
        st0 = __builtin_amdgcn_mfma_f32_32x32x16_bf16(
                *(const bf16x8*)(kb0 + ((1 * 32 + hi * 16) ^ swz)), bqf[1], st0, 0, 0, 0);
        st0 = __builtin_amdgcn_mfma_f32_32x32x16_bf16(
                *(const bf16x8*)(kb0 + ((2 * 32 + hi * 16) ^ swz)), bqf[2], st0, 0, 0, 0);
        st0 = __builtin_amdgcn_mfma_f32_32x32x16_bf16(
                *(const bf16x8*)(kb0 + ((3 * 32 + hi * 16) ^ swz)), bqf[3], st0, 0, 0, 0);
        if (two) {
          const char* kb1 = kb0 + 32 * 128;
          f32x16 a;
          a = __builtin_amdgcn_mfma_f32_32x32x16_bf16(
                *(const bf16x8*)(kb1 + ((0 * 32 + hi * 16) ^ swz)), bqf[0], zc, 0, 0, 0);
          a = __builtin_amdgcn_mfma_f32_32x32x16_bf16(
                *(const bf16x8*)(kb1 + ((1 * 32 + hi * 16) ^ swz)), bqf[1], a, 0, 0, 0);
          a = __builtin_amdgcn_mfma_f32_32x32x16_bf16(
                *(const bf16x8*)(kb1 + ((2 * 32 + hi * 16) ^ swz)), bqf[2], a, 0, 0, 0);
          a = __builtin_amdgcn_mfma_f32_32x32x16_bf16(
                *(const bf16x8*)(kb1 + ((3 * 32 + hi * 16) ^ swz)), bqf[3], a, 0, 0, 0);
          st1 = a;
        }
        __builtin_amdgcn_s_setprio(0);
      }
      // ---- causal mask (diagonal region only) ----
      if (n0 + 63 > q0) {
        #pragma unroll
        for (int rr = 0; rr < 16; ++rr) {
          int key0 = n0 + (rr & 3) + 8 * (rr >> 2) + 4 * hi;
          if (key0 > q0 + col) st0[rr] = -INFINITY;
          if (two) { if (key0 + 32 > q0 + col) st1[rr] = -INFINITY; }
        }
      }
      // ---- softmax: v_max3 tree, lane-local defer-max ----
      float mm;
      {
        float g0 = max3f(st0[0],  st0[1],  st0[2]);
        float g1 = max3f(st0[3],  st0[4],  st0[5]);
        float g2 = max3f(st0[6],  st0[7],  st0[8]);
        float g3 = max3f(st0[9],  st0[10], st0[11]);
        float g4 = max3f(st0[12], st0[13], st0[14]);
        mm = fmaxf(max3f(g0, g1, g2), max3f(g3, g4, st0[15]));
        if (two) {
          float h0 = max3f(st1[0],  st1[1],  st1[2]);
          float h1 = max3f(st1[3],  st1[4],  st1[5]);
          float h2 = max3f(st1[6],  st1[7],  st1[8]);
          float h3 = max3f(st1[9],  st1[10], st1[11]);
          float h4 = max3f(st1[12], st1[13], st1[14]);
          mm = fmaxf(mm, fmaxf(max3f(h0, h1, h2), max3f(h3, h4, st1[15])));
        }
      }
      if (!__all(mm <= m + 8.f)) {           // rare rescale path
        float mf = fmaxf(mm, __shfl_xor(mm, 32));
        float mnew = fmaxf(m, mf);
        float corr = exp2fast(m - mnew);
        m = mnew;
        lacc[0] *= corr;
        #pragma unroll
        for (int rr = 0; rr < 16; ++rr) { ot0[rr] *= corr; ot1[rr] *= corr; }
      }
      {
        bf16x8 w;
        #pragma unroll
        for (int e = 0; e < 8; ++e) w[e] = (__bf16)exp2fast(st0[e] - m);
        pf0 = w;
      }
      {
        bf16x8 w;
        #pragma unroll
        for (int e = 0; e < 8; ++e) w[e] = (__bf16)exp2fast(st0[8 + e] - m);
        pf1 = w;
      }
      if (two) {
        bf16x8 w;
        #pragma unroll
        for (int e = 0; e < 8; ++e) w[e] = (__bf16)exp2fast(st1[e] - m);
        pf2 = w;
        bf16x8 w2;
        #pragma unroll
        for (int e = 0; e < 8; ++e) w2[e] = (__bf16)exp2fast(st1[8 + e] - m);
        pf3 = w2;
      }
      // ---- PV + l on matrix pipe ----
      {
        const char* vb0 = (const char*)baseV + col * 128;
        const char* vb1 = vb0 + 32 * 128;
        __builtin_amdgcn_s_setprio(1);
        lacc = __builtin_amdgcn_mfma_f32_32x32x16_bf16(ones, pf0, lacc, 0, 0, 0);
        lacc = __builtin_amdgcn_mfma_f32_32x32x16_bf16(ones, pf1, lacc, 0, 0, 0);
        #pragma unroll
        for (int ks = 0; ks < 2; ++ks) {
          bf16x8 pw = ks ? pf1 : pf0;
          bf16x8 av0 = *(const bf16x8*)(vb0 + ((ks * 32 + hi * 16) ^ swz));
          bf16x8 av1 = *(const bf16x8*)(vb1 + ((ks * 32 + hi * 16) ^ swz));
          ot0 = __builtin_amdgcn_mfma_f32_32x32x16_bf16(av0, pw, ot0, 0, 0, 0);
          ot1 = __builtin_amdgcn_mfma_f32_32x32x16_bf16(av1, pw, ot1, 0, 0, 0);
        }
        if (two) {
          lacc = __builtin_amdgcn_mfma_f32_32x32x16_bf16(ones, pf2, lacc, 0, 0, 0);
          lacc = __builtin_amdgcn_mfma_f32_32x32x16_bf16(ones, pf3, lacc, 0, 0, 0);
          #pragma unroll
          for (int ks = 2; ks < 4; ++ks) {
            bf16x8 pw = (ks == 3) ? pf3 : pf2;
            bf16x8 av0 = *(const bf16x8*)(vb0 + ((ks * 32 + hi * 16) ^ swz));
            bf16x8 av1 = *(const bf16x8*)(vb1 + ((ks * 32 + hi * 16) ^ swz));
            ot0 = __builtin_amdgcn_mfma_f32_32x32x16_bf16(av0, pw, ot0, 0, 0, 0);
            ot1 = __builtin_amdgcn_mfma_f32_32x32x16_bf16(av1, pw, ot1, 0, 0, 0);
          }
        }
        __builtin_amdgcn_s_setprio(0);
      }
    }
    __builtin_amdgcn_sched_barrier(0);
  }

  // ---- normalize + store ----
  float inv = 1.f / lacc[0];
  unsigned short* yrow = y + ((size_t)b * T_ + q0 + col) * C_ + h * D_;
  #pragma unroll
  for (int a = 0; a < 4; ++a) {
    ushort4 o4;
    o4.x = f2bf(ot0[4 * a + 0] * inv);
    o4.y = f2bf(ot0[4 * a + 1] * inv);
    o4.z = f2bf(ot0[4 * a + 2] * inv);
    o4.w = f2bf(ot0[4 * a + 3] * inv);
    *(ushort4*)(yrow + 8 * a + 4 * hi) = o4;
  }
  #pragma unroll
  for (int a = 0; a < 4; ++a) {
    ushort4 o4;
    o4.x = f2bf(ot1[4 * a + 0] * inv);
    o4.y = f2bf(ot1[4 * a + 1] * inv);
    o4.z = f2bf(ot1[4 * a + 2] * inv);
    o4.w = f2bf(ot1[4 * a + 3] * inv);
    *(ushort4*)(yrow + 32 + 8 * a + 4 * hi) = o4;
  }
}

extern "C" void kernel_launch(void* const* d_in, const int* in_sizes, int n_in,
                              void* d_out, int out_size, void* d_ws, size_t ws_size,
                              hipStream_t stream) {
  const float* x  = (const float*)d_in[0];
  const float* Wq = (const float*)d_in[1];
  const float* bq = (const float*)d_in[2];
  const float* Wk = (const float*)d_in[3];
  const float* bk = (const float*)d_in[4];
  const float* Wv = (const float*)d_in[5];
  const float* bv = (const float*)d_in[6];
  const float* Wp = (const float*)d_in[7];
  const float* bp = (const float*)d_in[8];
  float* out = (float*)d_out;

  char* ws = (char*)d_ws;
  unsigned short* xb    = (unsigned short*)ws; ws += (size_t)M_ * C_ * 2;
  unsigned short* wqkvt = (unsigned short*)ws; ws += (size_t)3 * C_ * C_ * 2;
  unsigned short* wpt   = (unsigned short*)ws; ws += (size_t)C_ * C_ * 2;
  unsigned short* qb    = (unsigned short*)ws; ws += (size_t)M_ * C_ * 2;
  unsigned short* kb    = (unsigned short*)ws; ws += (size_t)M_ * C_ * 2;
  unsigned short* vtb   = (unsigned short*)ws; ws += (size_t)M_ * C_ * 2;
  unsigned short* yb    = (unsigned short*)ws; ws += (size_t)M_ * C_ * 2;

  prep<<<dim3(32, 32, 12), dim3(32, 8), 0, stream>>>(x, Wq, Wk, Wv, Wp, xb, wqkvt, wpt);

  const float qscale = 0.125f * 1.4426950408889634f;  // 1/sqrt(64) * log2(e)
  gemm_qkv<<<dim3(3 * C_ / 128, M_ / 128), dim3(256), 0, stream>>>(
      xb, wqkvt, bq, bk, bv, qb, kb, vtb, qscale);

  attn14<<<dim3(512), dim3(512), 0, stream>>>(qb, kb, vtb, yb);

  gemm_proj<<<dim3(C_ / 128, M_ / 128), dim3(256), 0, stream>>>(yb, wpt, bp, out);
}

// Round 18
// 154.769 us; speedup vs baseline: 1.0552x; 1.0552x over previous
//
#include <hip/hip_runtime.h>
#include <hip/hip_bf16.h>

#define B_ 4
#define T_ 2048
#define C_ 1024
#define H_ 16
#define D_ 64
#define M_ (B_*T_)   // 8192

typedef __bf16 bf16x8 __attribute__((ext_vector_type(8)));
typedef float  f32x4  __attribute__((ext_vector_type(4)));
typedef float  f32x16 __attribute__((ext_vector_type(16)));

__device__ __forceinline__ unsigned short f2bf(float f) {
  unsigned u = __builtin_bit_cast(unsigned, f);
  u += 0x7FFF + ((u >> 16) & 1);   // round-to-nearest-even
  return (unsigned short)(u >> 16);
}

__device__ __forceinline__ float exp2fast(float x) {
#if __has_builtin(__builtin_amdgcn_exp2f)
  return __builtin_amdgcn_exp2f(x);
#else
  float r; asm("v_exp_f32 %0, %1" : "=v"(r) : "v"(x)); return r;
#endif
}

__device__ __forceinline__ float max3f(float a, float b, float c) {
  return fmaxf(fmaxf(a, b), c);   // fuses to v_max3_f32
}

__device__ __forceinline__ void gload_lds16(const void* g, void* l) {
  __builtin_amdgcn_global_load_lds(
      (const __attribute__((address_space(1))) void*)g,
      (__attribute__((address_space(3))) void*)l, 16, 0, 0);
}

// ------------- fused prep: weight transpose+convert (z=0..3) + x f32->bf16 (z=4..11) -----
__global__ void prep(const float* __restrict__ x,
                     const float* __restrict__ w0, const float* __restrict__ w1,
                     const float* __restrict__ w2, const float* __restrict__ w3,
                     unsigned short* __restrict__ xb,
                     unsigned short* __restrict__ tqkv,
                     unsigned short* __restrict__ tp) {
  __shared__ float tile[32][33];
  const int z = blockIdx.z;
  if (z >= 4) {
    // x conversion: 8 slices x 1024 blocks x 256 thr x 4 f32 = 8.4M elements
    int tid = threadIdx.y * 32 + threadIdx.x;
    int i = (((z - 4) * 1024) + (blockIdx.y * 32 + blockIdx.x)) * 256 + tid;
    float4 v = ((const float4*)x)[i];
    ushort4 o;
    o.x = f2bf(v.x); o.y = f2bf(v.y); o.z = f2bf(v.z); o.w = f2bf(v.w);
    ((ushort4*)xb)[i] = o;
    return;
  }
  const float* src; unsigned short* dst;
  switch (z) {
    case 0: src = w0; dst = tqkv; break;
    case 1: src = w1; dst = tqkv + (size_t)C_ * C_; break;
    case 2: src = w2; dst = tqkv + (size_t)2 * C_ * C_; break;
    default: src = w3; dst = tp; break;
  }
  int bx = blockIdx.x * 32;  // n base
  int by = blockIdx.y * 32;  // k base
  int tx = threadIdx.x, ty = threadIdx.y;
  #pragma unroll
  for (int j = 0; j < 4; ++j)
    tile[ty + 8*j][tx] = src[(size_t)(by + ty + 8*j) * C_ + bx + tx];
  __syncthreads();
  #pragma unroll
  for (int j = 0; j < 4; ++j)
    dst[(size_t)(bx + ty + 8*j) * C_ + by + tx] = f2bf(tile[tx][ty + 8*j]);
}

// ---------------- fused QKV GEMM: xb[M][K] @ wqkvt[3N][K]^T ----------------
// Epilogue: per-wave XOR-swizzled LDS repack -> coalesced 16B/lane stores.
__global__ __launch_bounds__(256, 2)
void gemm_qkv(const unsigned short* __restrict__ A,
              const unsigned short* __restrict__ Bt,
              const float* __restrict__ bq, const float* __restrict__ bk,
              const float* __restrict__ bv,
              unsigned short* __restrict__ qout, unsigned short* __restrict__ kout,
              unsigned short* __restrict__ vout, float qscale)
{
  __shared__ unsigned short ls[2 * 128 * 64];   // 32KB
  unsigned short* lsA = ls;
  unsigned short* lsB = ls + 128 * 64;
  const int wave = threadIdx.x >> 6;
  const int lane = threadIdx.x & 63;
  const int rowBase = blockIdx.y * 128;
  const int colBase = blockIdx.x * 128;
  const int rowOff = (wave >> 1) * 64;
  const int colOff = (wave & 1) * 64;
  const int lr = lane & 15;
  const int lg = lane >> 4;

  f32x4 acc[4][4] = {};

  const int chunkRow = lane >> 3;
  const int srcColE  = (((lane & 7) ^ (lane >> 3)) * 8);

  for (int k0 = 0; k0 < C_; k0 += 64) {
    #pragma unroll
    for (int c = 0; c < 4; ++c) {
      int chunk = c * 4 + wave;
      int r = chunk * 8 + chunkRow;
      gload_lds16(A  + (size_t)(rowBase + r) * C_ + k0 + srcColE, &lsA[chunk * 512]);
      gload_lds16(Bt + (size_t)(colBase + r) * C_ + k0 + srcColE, &lsB[chunk * 512]);
    }
    __syncthreads();
    #pragma unroll
    for (int kk = 0; kk < 2; ++kk) {
      bf16x8 af[4], bfr[4];
      const int kbyte = (kk * 32 + lg * 8) * 2;
      #pragma unroll
      for (int m = 0; m < 4; ++m) {
        int row = rowOff + m * 16 + lr;
        af[m] = *(const bf16x8*)((const char*)lsA + row * 128 + (kbyte ^ ((row & 7) << 4)));
      }
      #pragma unroll
      for (int n = 0; n < 4; ++n) {
        int row = colOff + n * 16 + lr;
        bfr[n] = *(const bf16x8*)((const char*)lsB + row * 128 + (kbyte ^ ((row & 7) << 4)));
      }
      #pragma unroll
      for (int m = 0; m < 4; ++m)
        #pragma unroll
        for (int n = 0; n < 4; ++n)
          acc[m][n] = __builtin_amdgcn_mfma_f32_16x16x32_bf16(af[m], bfr[n], acc[m][n], 0, 0, 0);
    }
    __syncthreads();
  }

  const int mid = colBase >> 10;                 // 0=Q 1=K 2=V (block-uniform)
  const float* bias = (mid == 0) ? bq : (mid == 1) ? bk : bv;
  const float oscale = (mid == 0) ? qscale : 1.f;
  unsigned short* outp = (mid == 0) ? qout : (mid == 1) ? kout : vout;

  char* rpb = (char*)(ls + wave * 4096);         // per-wave 8KB repack region
  const int colW = colBase + colOff;
  const int h  = (colW & 1023) >> 6;
  const int b  = (rowBase + rowOff) >> 11;
  const int tb = (rowBase + rowOff) & 2047;

  #pragma unroll
  for (int m = 0; m < 4; ++m)
    #pragma unroll
    for (int n = 0; n < 4; ++n) {
      int colL = n * 16 + lr;
      float bs = bias[(colW + colL) & 1023];
      #pragma unroll
      for (int j = 0; j < 4; ++j) {
        int rowL = m * 16 + lg * 4 + j;
        unsigned short v = f2bf((acc[m][n][j] + bs) * oscale);
        int wr, wc;
        if (mid == 2) {
          int t2 = (rowL & ~12) | ((rowL & 4) << 1) | ((rowL & 8) >> 1);
          wr = colL; wc = t2;
        } else {
          wr = rowL; wc = colL;
        }
        *(unsigned short*)(rpb + wr * 128 + ((wc * 2) ^ ((wr & 7) << 4))) = v;
      }
    }

  const int rb = lane >> 3;
  const int g  = lane & 7;
  if (mid == 2) {
    unsigned short* ob = outp + (((size_t)b * H_ + h) * D_) * T_ + tb;
    #pragma unroll
    for (int p = 0; p < 8; ++p) {
      int d = rb + p * 8;
      bf16x8 v = *(const bf16x8*)(rpb + d * 128 + ((g * 16) ^ ((d & 7) << 4)));
      *(bf16x8*)(ob + (size_t)d * T_ + g * 8) = v;
    }
  } else {
    unsigned short* ob = outp + (((size_t)b * H_ + h) * T_ + tb) * D_;
    #pragma unroll
    for (int p = 0; p < 8; ++p) {
      int r = rb + p * 8;
      bf16x8 v = *(const bf16x8*)(rpb + r * 128 + ((g * 16) ^ ((r & 7) << 4)));
      *(bf16x8*)(ob + (size_t)r * D_ + g * 8) = v;
    }
  }
}

// ---------------- final projection GEMM: yb[M][K] @ wpt[N][K]^T -> f32 ----------------
__global__ __launch_bounds__(256, 2)
void gemm_proj(const unsigned short* __restrict__ A,
               const unsigned short* __restrict__ Bt,
               const float* __restrict__ bias,
               float* __restrict__ Cout)
{
  __shared__ unsigned short lsA[128 * 64];
  __shared__ unsigned short lsB[128 * 64];
  const int wave = threadIdx.x >> 6;
  const int lane = threadIdx.x & 63;
  const int rowBase = blockIdx.y * 128;
  const int colBase = blockIdx.x * 128;
  const int rowOff = (wave >> 1) * 64;
  const int colOff = (wave & 1) * 64;
  const int lr = lane & 15;
  const int lg = lane >> 4;

  f32x4 acc[4][4] = {};

  const int chunkRow = lane >> 3;
  const int srcColE  = (((lane & 7) ^ (lane >> 3)) * 8);

  for (int k0 = 0; k0 < C_; k0 += 64) {
    #pragma unroll
    for (int c = 0; c < 4; ++c) {
      int chunk = c * 4 + wave;
      int r = chunk * 8 + chunkRow;
      gload_lds16(A  + (size_t)(rowBase + r) * C_ + k0 + srcColE, &lsA[chunk * 512]);
      gload_lds16(Bt + (size_t)(colBase + r) * C_ + k0 + srcColE, &lsB[chunk * 512]);
    }
    __syncthreads();
    #pragma unroll
    for (int kk = 0; kk < 2; ++kk) {
      bf16x8 af[4], bfr[4];
      const int kbyte = (kk * 32 + lg * 8) * 2;
      #pragma unroll
      for (int m = 0; m < 4; ++m) {
        int row = rowOff + m * 16 + lr;
        af[m] = *(const bf16x8*)((const char*)lsA + row * 128 + (kbyte ^ ((row & 7) << 4)));
      }
      #pragma unroll
      for (int n = 0; n < 4; ++n) {
        int row = colOff + n * 16 + lr;
        bfr[n] = *(const bf16x8*)((const char*)lsB + row * 128 + (kbyte ^ ((row & 7) << 4)));
      }
      #pragma unroll
      for (int m = 0; m < 4; ++m)
        #pragma unroll
        for (int n = 0; n < 4; ++n)
          acc[m][n] = __builtin_amdgcn_mfma_f32_16x16x32_bf16(af[m], bfr[n], acc[m][n], 0, 0, 0);
    }
    __syncthreads();
  }

  #pragma unroll
  for (int m = 0; m < 4; ++m) {
    int row0 = rowBase + rowOff + m * 16 + lg * 4;
    #pragma unroll
    for (int n = 0; n < 4; ++n) {
      int col = colBase + colOff + n * 16 + lr;
      float bs = bias[col];
      #pragma unroll
      for (int j = 0; j < 4; ++j)
        Cout[(size_t)(row0 + j) * C_ + col] = acc[m][n][j] + bs;
    }
  }
}

// -------- causal flash attention: LDS-staged, K 3-buf / V 2-buf, counted vmcnt ----------
// l computed on the MATRIX pipe: lacc = mfma(ones, pf, lacc) -> every row = sum_k P[k][q].
// max reduction via v_max3_f32 trees. Softmax otherwise lane-local, defer-max THR=8.
__global__ __launch_bounds__(256, 2)
void attn12(const unsigned short* __restrict__ q,
            const unsigned short* __restrict__ k,
            const unsigned short* __restrict__ vp,
            unsigned short* __restrict__ y)
{
  __shared__ unsigned short lsK[3][64 * 64];   // 24 KB
  __shared__ unsigned short lsV[2][64 * 64];   // 16 KB
  const int tid  = threadIdx.x;
  const int wave = tid >> 6;
  const int lane = tid & 63;
  const int col  = lane & 31;
  const int hi   = lane >> 5;

  const int bid = blockIdx.x;            // 0..1023
  const int xcd = bid & 7;
  const int idx = bid >> 3;              // 0..127
  const int bh  = xcd * 8 + (idx & 7);   // 8 heads per XCD
  const int ss  = 15 - (idx >> 3);       // supertile 15..0 (longest first)
  const int b = bh >> 4, h = bh & 15;

  const unsigned short* qh = q  + (size_t)bh * T_ * D_;
  const unsigned short* kh = k  + (size_t)bh * T_ * D_;
  const unsigned short* vh = vp + (size_t)bh * D_ * T_;

  const int srow = tid >> 3;                             // 0..31
  const int srcE = ((tid & 7) * 8) ^ ((srow & 7) << 3);
  const unsigned short* ksrc = kh + srow * D_ + srcE;
  const unsigned short* vsrc = vh + srow * T_ + srcE;

  const int swz = (col & 7) << 4;
  const f32x16 zc = {};

  bf16x8 ones;
  #pragma unroll
  for (int e = 0; e < 8; ++e) ones[e] = (__bf16)1.0f;

  const int q0 = ss * 128 + wave * 32;
  const int nsteps = 2 * ss + 2;

  bf16x8 bqf[4];
  {
    const unsigned short* qrow = qh + (size_t)(q0 + col) * D_ + hi * 8;
    #pragma unroll
    for (int ks = 0; ks < 4; ++ks) bqf[ks] = *(const bf16x8*)(qrow + ks * 16);
  }

  f32x16 ot0 = {}, ot1 = {}, lacc = {};
  float m = -INFINITY;
  bf16x8 pf0, pf1, pf2, pf3;

  auto STAGEK = [&](int t) {
    unsigned short* bK = &lsK[0][0] + (t % 3) * 4096;
    const unsigned short* kg = ksrc + (size_t)t * 64 * D_;
    gload_lds16(kg,           bK + tid * 8);
    gload_lds16(kg + 32 * D_, bK + (tid + 256) * 8);
  };
  auto STAGEV = [&](int t) {
    unsigned short* bV = &lsV[0][0] + (t & 1) * 4096;
    const unsigned short* vg = vsrc + t * 64;
    gload_lds16(vg,           bV + tid * 8);
    gload_lds16(vg + 32 * T_, bV + (tid + 256) * 8);
  };

  STAGEK(0);
  STAGEV(0);
  STAGEK(1);

  for (int s = 0; s < nsteps; ++s) {
    if (s + 1 < nsteps) {
      asm volatile("s_waitcnt vmcnt(2)" ::: "memory");
    } else {
      asm volatile("s_waitcnt vmcnt(0)" ::: "memory");
    }
    __builtin_amdgcn_s_barrier();
    __builtin_amdgcn_sched_barrier(0);
    if (s + 1 < nsteps) STAGEV(s + 1);
    if (s + 2 < nsteps) STAGEK(s + 2);

    const int n0 = s * 64;
    if (n0 <= q0 + 31) {
      const bool two = (n0 < q0);
      const unsigned short* baseK = &lsK[0][0] + (s % 3) * 4096;
      const unsigned short* baseV = &lsV[0][0] + (s & 1) * 4096;
      // ---- QK^T ----
      f32x16 st0, st1;
      {
        const char* kb0 = (const char*)baseK + col * 128;
        __builtin_amdgcn_s_setprio(1);
        st0 = __builtin_amdgcn_mfma_f32_32x32x16_bf16(
                *(const bf16x8*)(kb0 + ((0 * 32 + hi * 16) ^ swz)), bqf[0], zc, 0, 0, 0);
        st0 = __builtin_amdgcn_mfma_f32_32x32x16_bf16(
                *(const bf16x8*)(kb0 + ((1 * 32 + hi * 16) ^ swz)), bqf[1], st0, 0, 0, 0);
        st0 = __builtin_amdgcn_mfma_f32_32x32x16_bf16(
                *(const bf16x8*)(kb0 + ((2 * 32 + hi * 16) ^ swz)), bqf[2], st0, 0, 0, 0);
        st0 = __builtin_amdgcn_mfma_f32_32x32x16_bf16(
                *(const bf16x8*)(kb0 + ((3 * 32 + hi * 16) ^ swz)), bqf[3], st0, 0, 0, 0);
        if (two) {
          const char* kb1 = kb0 + 32 * 128;
          f32x16 a;
          a = __builtin_amdgcn_mfma_f32_32x32x16_bf16(
                *(const bf16x8*)(kb1 + ((0 * 32 + hi * 16) ^ swz)), bqf[0], zc, 0, 0, 0);
          a = __builtin_amdgcn_mfma_f32_32x32x16_bf16(
                *(const bf16x8*)(kb1 + ((1 * 32 + hi * 16) ^ swz)), bqf[1], a, 0, 0, 0);
          a = __builtin_amdgcn_mfma_f32_32x32x16_bf16(
                *(const bf16x8*)(kb1 + ((2 * 32 + hi * 16) ^ swz)), bqf[2], a, 0, 0, 0);
          a = __builtin_amdgcn_mfma_f32_32x32x16_bf16(
                *(const bf16x8*)(kb1 + ((3 * 32 + hi * 16) ^ swz)), bqf[3], a, 0, 0, 0);
          st1 = a;
        }
        __builtin_amdgcn_s_setprio(0);
      }
      // ---- causal mask (diagonal region only) ----
      if (n0 + 63 > q0) {
        #pragma unroll
        for (int rr = 0; rr < 16; ++rr) {
          int key0 = n0 + (rr & 3) + 8 * (rr >> 2) + 4 * hi;
          if (key0 > q0 + col) st0[rr] = -INFINITY;
          if (two) { if (key0 + 32 > q0 + col) st1[rr] = -INFINITY; }
        }
      }
      // ---- softmax: v_max3 tree, lane-local defer-max ----
      float mm;
      {
        float g0 = max3f(st0[0],  st0[1],  st0[2]);
        float g1 = max3f(st0[3],  st0[4],  st0[5]);
        float g2 = max3f(st0[6],  st0[7],  st0[8]);
        float g3 = max3f(st0[9],  st0[10], st0[11]);
        float g4 = max3f(st0[12], st0[13], st0[14]);
        mm = fmaxf(max3f(g0, g1, g2), max3f(g3, g4, st0[15]));
        if (two) {
          float h0 = max3f(st1[0],  st1[1],  st1[2]);
          float h1 = max3f(st1[3],  st1[4],  st1[5]);
          float h2 = max3f(st1[6],  st1[7],  st1[8]);
          float h3 = max3f(st1[9],  st1[10], st1[11]);
          float h4 = max3f(st1[12], st1[13], st1[14]);
          mm = fmaxf(mm, fmaxf(max3f(h0, h1, h2), max3f(h3, h4, st1[15])));
        }
      }
      if (!__all(mm <= m + 8.f)) {           // rare rescale path
        float mf = fmaxf(mm, __shfl_xor(mm, 32));
        float mnew = fmaxf(m, mf);
        float corr = exp2fast(m - mnew);
        m = mnew;
        lacc[0] *= corr;                     // only [0] is read; mfma deltas are row-uniform
        #pragma unroll
        for (int rr = 0; rr < 16; ++rr) { ot0[rr] *= corr; ot1[rr] *= corr; }
      }
      {
        bf16x8 w;
        #pragma unroll
        for (int e = 0; e < 8; ++e) w[e] = (__bf16)exp2fast(st0[e] - m);
        pf0 = w;
      }
      {
        bf16x8 w;
        #pragma unroll
        for (int e = 0; e < 8; ++e) w[e] = (__bf16)exp2fast(st0[8 + e] - m);
        pf1 = w;
      }
      if (two) {
        bf16x8 w;
        #pragma unroll
        for (int e = 0; e < 8; ++e) w[e] = (__bf16)exp2fast(st1[e] - m);
        pf2 = w;
        bf16x8 w2;
        #pragma unroll
        for (int e = 0; e < 8; ++e) w2[e] = (__bf16)exp2fast(st1[8 + e] - m);
        pf3 = w2;
      }
      // ---- PV + l on matrix pipe ----
      {
        const char* vb0 = (const char*)baseV + col * 128;
        const char* vb1 = vb0 + 32 * 128;
        __builtin_amdgcn_s_setprio(1);
        lacc = __builtin_amdgcn_mfma_f32_32x32x16_bf16(ones, pf0, lacc, 0, 0, 0);
        lacc = __builtin_amdgcn_mfma_f32_32x32x16_bf16(ones, pf1, lacc, 0, 0, 0);
        #pragma unroll
        for (int ks = 0; ks < 2; ++ks) {
          bf16x8 pw = ks ? pf1 : pf0;
          bf16x8 av0 = *(const bf16x8*)(vb0 + ((ks * 32 + hi * 16) ^ swz));
          bf16x8 av1 = *(const bf16x8*)(vb1 + ((ks * 32 + hi * 16) ^ swz));
          ot0 = __builtin_amdgcn_mfma_f32_32x32x16_bf16(av0, pw, ot0, 0, 0, 0);
          ot1 = __builtin_amdgcn_mfma_f32_32x32x16_bf16(av1, pw, ot1, 0, 0, 0);
        }
        if (two) {
          lacc = __builtin_amdgcn_mfma_f32_32x32x16_bf16(ones, pf2, lacc, 0, 0, 0);
          lacc = __builtin_amdgcn_mfma_f32_32x32x16_bf16(ones, pf3, lacc, 0, 0, 0);
          #pragma unroll
          for (int ks = 2; ks < 4; ++ks) {
            bf16x8 pw = (ks == 3) ? pf3 : pf2;
            bf16x8 av0 = *(const bf16x8*)(vb0 + ((ks * 32 + hi * 16) ^ swz));
            bf16x8 av1 = *(const bf16x8*)(vb1 + ((ks * 32 + hi * 16) ^ swz));
            ot0 = __builtin_amdgcn_mfma_f32_32x32x16_bf16(av0, pw, ot0, 0, 0, 0);
            ot1 = __builtin_amdgcn_mfma_f32_32x32x16_bf16(av1, pw, ot1, 0, 0, 0);
          }
        }
        __builtin_amdgcn_s_setprio(0);
      }
    }
    __builtin_amdgcn_sched_barrier(0);
  }

  // ---- normalize + store (lacc[0] already holds the full 64-key sum per query) ----
  float inv = 1.f / lacc[0];
  unsigned short* yrow = y + ((size_t)b * T_ + q0 + col) * C_ + h * D_;
  #pragma unroll
  for (int a = 0; a < 4; ++a) {
    ushort4 o4;
    o4.x = f2bf(ot0[4 * a + 0] * inv);
    o4.y = f2bf(ot0[4 * a + 1] * inv);
    o4.z = f2bf(ot0[4 * a + 2] * inv);
    o4.w = f2bf(ot0[4 * a + 3] * inv);
    *(ushort4*)(yrow + 8 * a + 4 * hi) = o4;
  }
  #pragma unroll
  for (int a = 0; a < 4; ++a) {
    ushort4 o4;
    o4.x = f2bf(ot1[4 * a + 0] * inv);
    o4.y = f2bf(ot1[4 * a + 1] * inv);
    o4.z = f2bf(ot1[4 * a + 2] * inv);
    o4.w = f2bf(ot1[4 * a + 3] * inv);
    *(ushort4*)(yrow + 32 + 8 * a + 4 * hi) = o4;
  }
}

extern "C" void kernel_launch(void* const* d_in, const int* in_sizes, int n_in,
                              void* d_out, int out_size, void* d_ws, size_t ws_size,
                              hipStream_t stream) {
  const float* x  = (const float*)d_in[0];
  const float* Wq = (const float*)d_in[1];
  const float* bq = (const float*)d_in[2];
  const float* Wk = (const float*)d_in[3];
  const float* bk = (const float*)d_in[4];
  const float* Wv = (const float*)d_in[5];
  const float* bv = (const float*)d_in[6];
  const float* Wp = (const float*)d_in[7];
  const float* bp = (const float*)d_in[8];
  float* out = (float*)d_out;

  char* ws = (char*)d_ws;
  unsigned short* xb    = (unsigned short*)ws; ws += (size_t)M_ * C_ * 2;
  unsigned short* wqkvt = (unsigned short*)ws; ws += (size_t)3 * C_ * C_ * 2;
  unsigned short* wpt   = (unsigned short*)ws; ws += (size_t)C_ * C_ * 2;
  unsigned short* qb    = (unsigned short*)ws; ws += (size_t)M_ * C_ * 2;
  unsigned short* kb    = (unsigned short*)ws; ws += (size_t)M_ * C_ * 2;
  unsigned short* vtb   = (unsigned short*)ws; ws += (size_t)M_ * C_ * 2;
  unsigned short* yb    = (unsigned short*)ws; ws += (size_t)M_ * C_ * 2;

  prep<<<dim3(32, 32, 12), dim3(32, 8), 0, stream>>>(x, Wq, Wk, Wv, Wp, xb, wqkvt, wpt);

  const float qscale = 0.125f * 1.4426950408889634f;  // 1/sqrt(64) * log2(e)
  gemm_qkv<<<dim3(3 * C_ / 128, M_ / 128), dim3(256), 0, stream>>>(
      xb, wqkvt, bq, bk, bv, qb, kb, vtb, qscale);

  attn12<<<dim3(1024), dim3(256), 0, stream>>>(qb, kb, vtb, yb);

  gemm_proj<<<dim3(C_ / 128, M_ / 128), dim3(256), 0, stream>>>(yb, wpt, bp, out);
}